// Round 11
// baseline (95.743 us; speedup 1.0000x reference)
//
#include <hip/hip_runtime.h>
#include <math.h>

#define IMG    224
#define NVIEWS 6
#define BATCH  16
#define NPTS   32768
#define PLANE  (IMG * IMG)       // 50176
#define QR     56                // quarter-plane tile rows
#define TILE_ELEMS (QR * IMG)    // 12544 u32 = 50176 B dynamic LDS
#define NT     512
#define NWAVES (NT / 64)         // 8
#define QCAP   128               // per-wave queue entries (append<64 then drain)
#define NWG    (BATCH * NVIEWS * 4) // 384 -> 2 WGs/CU on all 256 CUs

typedef float fx4 __attribute__((ext_vector_type(4)));   // native vec for nontemporal

struct ViewTrig {
    float sa[NVIEWS], ca[NVIEWS], se[NVIEWS], ce[NVIEWS];
    float off0, off4;            // extreme splat offsets (footprint rectangle)
};

// fp32 ops with contraction OFF — these feed the pixel truncation and must
// round exactly like numpy's separate mul/add ufuncs.
__device__ __forceinline__ float fmul_(float a, float b) {
#pragma clang fp contract(off)
    return a * b;
}
__device__ __forceinline__ float fadd_(float a, float b) {
#pragma clang fp contract(off)
    return a + b;
}
__device__ __forceinline__ float fsub_(float a, float b) {
#pragma clang fp contract(off)
    return a - b;
}
// ((c + 1) * 0.5) * 223, truncate toward zero == astype(int32)
__device__ __forceinline__ int pix_(float c) {
    return (int)fmul_(fmul_(fadd_(c, 1.0f), 0.5f), 223.0f);
}

// Order-preserving float->uint map (monotone over all finite floats).
// Any finite zf maps to a value > 0, so 0 is a safe "empty pixel" sentinel.
__device__ __forceinline__ unsigned fmap_(float f) {
    unsigned b = __float_as_uint(f);
    return b ^ ((unsigned)((int)b >> 31) | 0x80000000u);
}
__device__ __forceinline__ float fmap_inv_(unsigned u) {
    unsigned b = (u & 0x80000000u) ? (u ^ 0x80000000u) : ~u;
    return __uint_as_float(b);
}

__device__ __forceinline__ int lane_prefix_(unsigned long long m) {
    return __builtin_amdgcn_mbcnt_hi((unsigned)(m >> 32),
           __builtin_amdgcn_mbcnt_lo((unsigned)m, 0));
}

// ---------------------------------------------------------------------------
// Fused single-scan render, quarter-plane tiles, 2 WGs/CU.
// One 512-thread WG per (b, v, quarter-plane). 58.5 KB LDS/WG -> two WGs
// co-resident per CU; 384 WGs cover all 256 CUs (round-10's 192x116KB
// config left 64 CUs idle and ran the 57.8 MB epilogue on 3/4 of the chip).
//
// Wave-private LDS queue: hits (~12% per quarter) are ballot-compacted into
// a private 128-entry queue (no atomics/barriers; wave-internal RAW through
// the in-order LDS pipe), drained 64 at a time at full lane density.
//
// Monotonicity: feat = zf*scale+bias, scale>0 -> max(feat) = f(max(zf));
// splat fmap(zf), convert in the epilogue. Strict-fp32 pixel chain is
// bit-exact vs numpy; zf/feat value is relaxed (tolerance 2e-2). zmin/zmax
// are exact selections -> all 4 WGs of a (b,v) agree bit-for-bit.
// ---------------------------------------------------------------------------
__global__ __launch_bounds__(NT, 4) void render_kernel(
    const float* __restrict__ pts, float* __restrict__ out, ViewTrig vt)
{
    extern __shared__ __align__(16) unsigned tile[];
    __shared__ uint2 wq[NWAVES][QCAP];              // 8 KB static
    __shared__ float smin[NWAVES], smax[NWAVES];

    // XCD-aware decode: xcd = bid&7 -> batches {xcd, xcd+8} pin to one XCD L2
    const int bid  = blockIdx.x;
    const int xcd  = bid & 7;
    const int slot = bid >> 3;            // 0..47
    const int hi   = (slot >= 24) ? 1 : 0;
    const int b    = xcd + 8 * hi;
    const int rem  = slot - 24 * hi;      // 0..23
    const int v    = rem >> 2;
    const int q    = rem & 3;
    const int bv   = b * NVIEWS + v;
    const int row0 = q * QR;
    const int row1 = row0 + QR - 1;

    const float sa = vt.sa[v], ca = vt.ca[v], se = vt.se[v], ce = vt.ce[v];
    const float off0 = vt.off0, off4 = vt.off4;
    const float4* p4 = (const float4*)(pts + (size_t)b * NPTS * 3);

    const int lane = threadIdx.x & 63;
    const int wave = threadIdx.x >> 6;

    // zero tile (b128 stores)
    {
        int4* t4 = (int4*)tile;
        for (int i = threadIdx.x; i < TILE_ELEMS / 4; i += NT)
            t4[i] = make_int4(0, 0, 0, 0);
    }
    __syncthreads();

    float zmin = INFINITY, zmax = -INFINITY;
    unsigned qcnt = 0;                    // wave-uniform queue fill

    // dense drain of 64 queue entries (all lanes useful)
    auto drain64 = [&]() {
        qcnt -= 64;
        const uint2 e = wq[wave][qcnt + lane];
        const unsigned fz = e.x, pk = e.y;
        const int cx0 = pk & 255;
        const int cx1 = (pk >> 8) & 255;
        const int r0 = max((int)((pk >> 16) & 255), row0) - row0;
        const int r1 = min((int)(pk >> 24), row1) - row0;
        #pragma unroll
        for (int dy = 0; dy < 3; ++dy) {
            const int ry = r0 + dy;
            const bool yok = (ry <= r1);
            #pragma unroll
            for (int dx = 0; dx < 3; ++dx) {
                const int cx = cx0 + dx;
                if (yok && (cx <= cx1)) atomicMax(&tile[ry * IMG + cx], fz);
            }
        }
    };

    auto do_point = [&](float x, float y, float z) {
        // strict fp32 chain -> pixel coordinates (bit-exact vs numpy)
        const float zr = fadd_(fmul_(x, sa), fmul_(z, ca));
        const float yr = fsub_(fmul_(y, ce), fmul_(zr, se));
        const float xr = fsub_(fmul_(x, ca), fmul_(z, sa));

        const int x0i = pix_(fadd_(xr, off0));
        const int x1i = pix_(fadd_(xr, off4));
        const int y0i = pix_(fadd_(yr, off0));
        const int y1i = pix_(fadd_(yr, off4));

        // relaxed depth (feeds minmax and the splat payload)
        const float zf = fmaf(zr, ce, y * se);
        zmin = fminf(zmin, zf);
        zmax = fmaxf(zmax, zf);

        const bool pred = (x1i >= 0) && (x0i <= IMG - 1) &&
                          (y1i >= row0) && (y0i <= row1);
        const unsigned long long m = __ballot(pred);
        if (pred) {
            const int cx0 = min(max(x0i, 0), IMG - 1);
            const int cx1 = min(max(x1i, 0), IMG - 1);
            const int cy0 = min(max(y0i, 0), IMG - 1);
            const int cy1 = min(max(y1i, 0), IMG - 1);
            const unsigned pk = (unsigned)cx0 | ((unsigned)cx1 << 8) |
                                ((unsigned)cy0 << 16) | ((unsigned)cy1 << 24);
            wq[wave][qcnt + lane_prefix_(m)] = make_uint2(fmap_(zf), pk);
        }
        qcnt += (unsigned)__popcll(m);    // wave-uniform
        if (qcnt >= 64) drain64();        // keeps qcnt < 64 (append adds <= 64)
    };

    #pragma unroll 4
    for (int k = 0; k < NPTS / (4 * NT); ++k) {   // 16 iterations
        const int g = threadIdx.x + k * NT;       // 4-point group index
        const float4 A = p4[3 * g + 0];
        const float4 B = p4[3 * g + 1];
        const float4 C = p4[3 * g + 2];
        do_point(A.x, A.y, A.z);
        do_point(A.w, B.x, B.y);
        do_point(B.z, B.w, C.x);
        do_point(C.y, C.z, C.w);
    }

    // final partial drain (< 64 entries)
    if (lane < (int)qcnt) {
        const uint2 e = wq[wave][lane];
        const unsigned fz = e.x, pk = e.y;
        const int cx0 = pk & 255;
        const int cx1 = (pk >> 8) & 255;
        const int r0 = max((int)((pk >> 16) & 255), row0) - row0;
        const int r1 = min((int)(pk >> 24), row1) - row0;
        #pragma unroll
        for (int dy = 0; dy < 3; ++dy) {
            const int ry = r0 + dy;
            const bool yok = (ry <= r1);
            #pragma unroll
            for (int dx = 0; dx < 3; ++dx) {
                const int cx = cx0 + dx;
                if (yok && (cx <= cx1)) atomicMax(&tile[ry * IMG + cx], fz);
            }
        }
    }

    // ---- block reduce zmin/zmax (exact selections, order-free) ----
    for (int o = 32; o > 0; o >>= 1) {
        zmin = fminf(zmin, __shfl_down(zmin, o, 64));
        zmax = fmaxf(zmax, __shfl_down(zmax, o, 64));
    }
    if (lane == 0) { smin[wave] = zmin; smax[wave] = zmax; }
    __syncthreads();   // also orders all LDS atomics before the epilogue
    if (threadIdx.x == 0) {
        float mn = smin[0], mx = smax[0];
        for (int w = 1; w < NWAVES; ++w) {
            mn = fminf(mn, smin[w]);
            mx = fmaxf(mx, smax[w]);
        }
        smin[0] = mn; smax[0] = mx;
    }
    __syncthreads();
    // feat = 0.3 + 0.7*(zf-zmin)/denom == zf*scale + bias  (err ~1e-6 << 2e-2)
    const float scale = 0.7f / ((smax[0] - smin[0]) + 1e-6f);
    const float bias  = 0.3f - smin[0] * scale;

    // ---- epilogue: tile -> feat -> channels 0,1,2 (non-temporal fx4) ----
    float* dst = out + ((size_t)bv * 3) * PLANE + (size_t)row0 * IMG;
    const uint4* src = (const uint4*)tile;
    for (int i = threadIdx.x; i < TILE_ELEMS / 4; i += NT) {
        const uint4 u = src[i];
        fx4 f;
        f.x = (u.x == 0u) ? 0.0f : fmaf(fmap_inv_(u.x), scale, bias);
        f.y = (u.y == 0u) ? 0.0f : fmaf(fmap_inv_(u.y), scale, bias);
        f.z = (u.z == 0u) ? 0.0f : fmaf(fmap_inv_(u.z), scale, bias);
        f.w = (u.w == 0u) ? 0.0f : fmaf(fmap_inv_(u.w), scale, bias);
        #pragma unroll
        for (int c = 0; c < 3; ++c)
            __builtin_nontemporal_store(f, (fx4*)(dst + (size_t)c * PLANE) + i);
    }
}

extern "C" void kernel_launch(void* const* d_in, const int* in_sizes, int n_in,
                              void* d_out, int out_size, void* d_ws, size_t ws_size,
                              hipStream_t stream)
{
    const float* pts = (const float*)d_in[0];
    float* out = (float*)d_out;

    // fp32-faithful constants (JAX x32 semantics), same as the passing rounds.
    ViewTrig vt;
    const float d2r = (float)(M_PI / 180.0);
    const float el_deg[NVIEWS] = {0.0f, 30.0f, -30.0f, 0.0f, 0.0f, 0.0f};
    for (int v = 0; v < NVIEWS; ++v) {
        float a = (float)(60 * v) * d2r;
        float e = el_deg[v] * d2r;
        vt.sa[v] = (float)sin((double)a);
        vt.ca[v] = (float)cos((double)a);
        vt.se[v] = (float)sin((double)e);
        vt.ce[v] = (float)cos((double)e);
    }
    {
        const float s = (float)(2.0 / 224.0);  // linspace end points, exact in fp32
        vt.off0 = -s;
        vt.off4 = s;
    }

    render_kernel<<<NWG, NT, TILE_ELEMS * sizeof(int), stream>>>(pts, out, vt);
}

// Round 12
// 88.740 us; speedup vs baseline: 1.0789x; 1.0789x over previous
//
#include <hip/hip_runtime.h>
#include <math.h>

#define IMG    224
#define NVIEWS 6
#define BATCH  16
#define NPTS   32768
#define PLANE  (IMG * IMG)       // 50176
#define HROWS  112               // half-plane tile
#define TILE_ELEMS (HROWS * IMG) // 25088 u32 = 100352 B dynamic LDS
#define NT     1024
#define NWAVES (NT / 64)         // 16
#define QCAP   128               // per-wave queue entries (append<64 then drain)
#define NWG    (BATCH * NVIEWS * 2) // 192

typedef float fx4 __attribute__((ext_vector_type(4)));   // native vec for nontemporal

struct ViewTrig {
    float sa[NVIEWS], ca[NVIEWS], se[NVIEWS], ce[NVIEWS];
    float off0, off4;            // extreme splat offsets (footprint rectangle)
};

// fp32 ops with contraction OFF — these feed the pixel truncation and must
// round exactly like numpy's separate mul/add ufuncs.
__device__ __forceinline__ float fmul_(float a, float b) {
#pragma clang fp contract(off)
    return a * b;
}
__device__ __forceinline__ float fadd_(float a, float b) {
#pragma clang fp contract(off)
    return a + b;
}
__device__ __forceinline__ float fsub_(float a, float b) {
#pragma clang fp contract(off)
    return a - b;
}
// ((c + 1) * 0.5) * 223, truncate toward zero == astype(int32)
__device__ __forceinline__ int pix_(float c) {
    return (int)fmul_(fmul_(fadd_(c, 1.0f), 0.5f), 223.0f);
}

// Order-preserving float->uint map (monotone over all finite floats).
// Any finite zf maps to a value > 0, so 0 is a safe "empty pixel" sentinel.
__device__ __forceinline__ unsigned fmap_(float f) {
    unsigned b = __float_as_uint(f);
    return b ^ ((unsigned)((int)b >> 31) | 0x80000000u);
}
__device__ __forceinline__ float fmap_inv_(unsigned u) {
    unsigned b = (u & 0x80000000u) ? (u ^ 0x80000000u) : ~u;
    return __uint_as_float(b);
}

__device__ __forceinline__ int lane_prefix_(unsigned long long m) {
    return __builtin_amdgcn_mbcnt_hi((unsigned)(m >> 32),
           __builtin_amdgcn_mbcnt_lo((unsigned)m, 0));
}

// ---------------------------------------------------------------------------
// BEST MEASURED CONFIG (round 10, 88.1 us) — reverted after the 384-WG
// quarter-tile rebalance (95.7 us) and global-list compaction (95.2 us)
// both regressed. Empirical finding: 2x geometry redundancy (half-plane
// tiles, 192 WGs) beats both 1x (global round-trip) and 4x (full-chip).
//
// Fused single-scan render with WAVE-PRIVATE LDS QUEUE compaction.
// One 1024-thread WG per (b, v, half-plane).
//
// Only ~23% of (point, half) passes hit the tile, but predicated atomics
// ISSUE on the LDS pipe regardless (9 issues/point). Fix: each wave
// ballot-compacts its hits into a private 128-entry LDS queue (no atomics,
// no barriers; wave-internal RAW through the in-order LDS pipe) and drains
// 64 at a time at ~100% lane density. LDS issues/point: ~9 -> ~3.
//
// Monotonicity: feat = zf*scale+bias, scale>0 -> max(feat) = f(max(zf));
// splat fmap(zf), convert in the epilogue. Strict-fp32 pixel chain is
// bit-exact vs numpy; zf/feat value is relaxed (tolerance 2e-2).
// ---------------------------------------------------------------------------
__global__ __launch_bounds__(NT, 4) void render_kernel(
    const float* __restrict__ pts, float* __restrict__ out, ViewTrig vt)
{
    extern __shared__ __align__(16) unsigned tile[];
    __shared__ uint2 wq[NWAVES][QCAP];              // 16 KB static
    __shared__ float smin[NWAVES], smax[NWAVES];

    // XCD-aware decode: xcd = bid&7 -> batches {xcd, xcd+8} pin to one XCD L2
    const int bid  = blockIdx.x;
    const int xcd  = bid & 7;
    const int slot = bid >> 3;            // 0..23
    const int hi   = (slot >= 12) ? 1 : 0;
    const int b    = xcd + 8 * hi;
    const int vh   = slot - 12 * hi;
    const int v    = vh >> 1;
    const int h    = vh & 1;
    const int bv   = b * NVIEWS + v;
    const int row0 = h * HROWS;
    const int row1 = row0 + HROWS - 1;

    const float sa = vt.sa[v], ca = vt.ca[v], se = vt.se[v], ce = vt.ce[v];
    const float off0 = vt.off0, off4 = vt.off4;
    const float4* p4 = (const float4*)(pts + (size_t)b * NPTS * 3);

    const int lane = threadIdx.x & 63;
    const int wave = threadIdx.x >> 6;

    // zero tile (b128 stores)
    {
        int4* t4 = (int4*)tile;
        for (int i = threadIdx.x; i < TILE_ELEMS / 4; i += NT)
            t4[i] = make_int4(0, 0, 0, 0);
    }
    __syncthreads();

    float zmin = INFINITY, zmax = -INFINITY;
    unsigned qcnt = 0;                    // wave-uniform queue fill

    // dense drain of 64 queue entries (all lanes useful)
    auto drain64 = [&]() {
        qcnt -= 64;
        const uint2 e = wq[wave][qcnt + lane];
        const unsigned fz = e.x, pk = e.y;
        const int cx0 = pk & 255;
        const int cx1 = (pk >> 8) & 255;
        const int r0 = max((int)((pk >> 16) & 255), row0) - row0;
        const int r1 = min((int)(pk >> 24), row1) - row0;
        #pragma unroll
        for (int dy = 0; dy < 3; ++dy) {
            const int ry = r0 + dy;
            const bool yok = (ry <= r1);
            #pragma unroll
            for (int dx = 0; dx < 3; ++dx) {
                const int cx = cx0 + dx;
                if (yok && (cx <= cx1)) atomicMax(&tile[ry * IMG + cx], fz);
            }
        }
    };

    auto do_point = [&](float x, float y, float z) {
        // strict fp32 chain -> pixel coordinates (bit-exact vs numpy)
        const float zr = fadd_(fmul_(x, sa), fmul_(z, ca));
        const float yr = fsub_(fmul_(y, ce), fmul_(zr, se));
        const float xr = fsub_(fmul_(x, ca), fmul_(z, sa));

        const int x0i = pix_(fadd_(xr, off0));
        const int x1i = pix_(fadd_(xr, off4));
        const int y0i = pix_(fadd_(yr, off0));
        const int y1i = pix_(fadd_(yr, off4));

        // relaxed depth (feeds minmax and the splat payload)
        const float zf = fmaf(zr, ce, y * se);
        zmin = fminf(zmin, zf);
        zmax = fmaxf(zmax, zf);

        const bool pred = (x1i >= 0) && (x0i <= IMG - 1) &&
                          (y1i >= row0) && (y0i <= row1);
        const unsigned long long m = __ballot(pred);
        if (pred) {
            const int cx0 = min(max(x0i, 0), IMG - 1);
            const int cx1 = min(max(x1i, 0), IMG - 1);
            const int cy0 = min(max(y0i, 0), IMG - 1);
            const int cy1 = min(max(y1i, 0), IMG - 1);
            const unsigned pk = (unsigned)cx0 | ((unsigned)cx1 << 8) |
                                ((unsigned)cy0 << 16) | ((unsigned)cy1 << 24);
            wq[wave][qcnt + lane_prefix_(m)] = make_uint2(fmap_(zf), pk);
        }
        qcnt += (unsigned)__popcll(m);    // wave-uniform
        if (qcnt >= 64) drain64();        // keeps qcnt < 64 (append adds <= 64)
    };

    #pragma unroll
    for (int k = 0; k < NPTS / (4 * NT); ++k) {   // 8 iterations
        const int g = threadIdx.x + k * NT;       // 4-point group index
        const float4 A = p4[3 * g + 0];
        const float4 B = p4[3 * g + 1];
        const float4 C = p4[3 * g + 2];
        do_point(A.x, A.y, A.z);
        do_point(A.w, B.x, B.y);
        do_point(B.z, B.w, C.x);
        do_point(C.y, C.z, C.w);
    }

    // final partial drain (< 64 entries)
    if (lane < (int)qcnt) {
        const uint2 e = wq[wave][lane];
        const unsigned fz = e.x, pk = e.y;
        const int cx0 = pk & 255;
        const int cx1 = (pk >> 8) & 255;
        const int r0 = max((int)((pk >> 16) & 255), row0) - row0;
        const int r1 = min((int)(pk >> 24), row1) - row0;
        #pragma unroll
        for (int dy = 0; dy < 3; ++dy) {
            const int ry = r0 + dy;
            const bool yok = (ry <= r1);
            #pragma unroll
            for (int dx = 0; dx < 3; ++dx) {
                const int cx = cx0 + dx;
                if (yok && (cx <= cx1)) atomicMax(&tile[ry * IMG + cx], fz);
            }
        }
    }

    // ---- block reduce zmin/zmax (exact selections, order-free) ----
    for (int o = 32; o > 0; o >>= 1) {
        zmin = fminf(zmin, __shfl_down(zmin, o, 64));
        zmax = fmaxf(zmax, __shfl_down(zmax, o, 64));
    }
    if (lane == 0) { smin[wave] = zmin; smax[wave] = zmax; }
    __syncthreads();   // also orders all LDS atomics before the epilogue
    if (threadIdx.x == 0) {
        float mn = smin[0], mx = smax[0];
        for (int w = 1; w < NWAVES; ++w) {
            mn = fminf(mn, smin[w]);
            mx = fmaxf(mx, smax[w]);
        }
        smin[0] = mn; smax[0] = mx;
    }
    __syncthreads();
    // feat = 0.3 + 0.7*(zf-zmin)/denom == zf*scale + bias  (err ~1e-6 << 2e-2)
    const float scale = 0.7f / ((smax[0] - smin[0]) + 1e-6f);
    const float bias  = 0.3f - smin[0] * scale;

    // ---- epilogue: tile -> feat -> channels 0,1,2 (non-temporal fx4) ----
    float* dst = out + ((size_t)bv * 3) * PLANE + (size_t)row0 * IMG;
    const uint4* src = (const uint4*)tile;
    for (int i = threadIdx.x; i < TILE_ELEMS / 4; i += NT) {
        const uint4 u = src[i];
        fx4 f;
        f.x = (u.x == 0u) ? 0.0f : fmaf(fmap_inv_(u.x), scale, bias);
        f.y = (u.y == 0u) ? 0.0f : fmaf(fmap_inv_(u.y), scale, bias);
        f.z = (u.z == 0u) ? 0.0f : fmaf(fmap_inv_(u.z), scale, bias);
        f.w = (u.w == 0u) ? 0.0f : fmaf(fmap_inv_(u.w), scale, bias);
        #pragma unroll
        for (int c = 0; c < 3; ++c)
            __builtin_nontemporal_store(f, (fx4*)(dst + (size_t)c * PLANE) + i);
    }
}

extern "C" void kernel_launch(void* const* d_in, const int* in_sizes, int n_in,
                              void* d_out, int out_size, void* d_ws, size_t ws_size,
                              hipStream_t stream)
{
    const float* pts = (const float*)d_in[0];
    float* out = (float*)d_out;

    // fp32-faithful constants (JAX x32 semantics), same as the passing rounds.
    ViewTrig vt;
    const float d2r = (float)(M_PI / 180.0);
    const float el_deg[NVIEWS] = {0.0f, 30.0f, -30.0f, 0.0f, 0.0f, 0.0f};
    for (int v = 0; v < NVIEWS; ++v) {
        float a = (float)(60 * v) * d2r;
        float e = el_deg[v] * d2r;
        vt.sa[v] = (float)sin((double)a);
        vt.ca[v] = (float)cos((double)a);
        vt.se[v] = (float)sin((double)e);
        vt.ce[v] = (float)cos((double)e);
    }
    {
        const float s = (float)(2.0 / 224.0);  // linspace end points, exact in fp32
        vt.off0 = -s;
        vt.off4 = s;
    }

    // Opt in to >64KB dynamic LDS (160 KiB/CU on gfx950). Graph-capture safe.
    (void)hipFuncSetAttribute(reinterpret_cast<const void*>(render_kernel),
                              hipFuncAttributeMaxDynamicSharedMemorySize,
                              TILE_ELEMS * (int)sizeof(int));

    render_kernel<<<NWG, NT, TILE_ELEMS * sizeof(int), stream>>>(pts, out, vt);
}